// Round 10
// baseline (169.099 us; speedup 1.0000x reference)
//
#include <hip/hip_runtime.h>
#include <math.h>

#define D_MODEL 1024
#define D_FF    4096
#define RANK    128
#define M_ROWS  8192

typedef _Float16 f16;
typedef _Float16 f16x8 __attribute__((ext_vector_type(8)));
typedef _Float16 f16x4 __attribute__((ext_vector_type(4)));
typedef float    f32x4 __attribute__((ext_vector_type(4)));

#define MFMA16(a, b, c) __builtin_amdgcn_mfma_f32_16x16x32_f16((a), (b), (c), 0, 0, 0)

__device__ __forceinline__ f16x8 ld8(const f16* p) { return *(const f16x8*)p; }

__device__ __forceinline__ f16x8 cvt8(float4 a0, float4 a1) {
    f16x8 r = { (f16)a0.x, (f16)a0.y, (f16)a0.z, (f16)a0.w,
                (f16)a1.x, (f16)a1.y, (f16)a1.z, (f16)a1.w };
    return r;
}

// Fast exact-gelu (proven R2/R4/R8, absmax 9.77e-4).
__device__ __forceinline__ float gelu_fast(float v) {
    float u  = v * 0.70710678118654752440f;
    float au = fabsf(u);
    float t  = __builtin_amdgcn_rcpf(__builtin_fmaf(0.3275911f, au, 1.0f));
    float e  = __expf(-au * au);
    float p  = __builtin_fmaf(1.061405429f, t, -1.453152027f);
    p = __builtin_fmaf(p, t, 1.421413741f);
    p = __builtin_fmaf(p, t, -0.284496736f);
    p = __builtin_fmaf(p, t, 0.254829592f);
    float er = __builtin_fmaf(-p * t, e, 1.0f);
    er = copysignf(er, u);
    return 0.5f * v * (1.0f + er);
}

// async global->LDS, 16 B per lane; LDS dest wave-uniform base + lane*16
#define GLOAD16(gp, lp) __builtin_amdgcn_global_load_lds(                     \
    (const __attribute__((address_space(1))) void*)(gp),                      \
    (__attribute__((address_space(3))) void*)(lp), 16, 0, 0)

// ---------------------------------------------------------------------------
// Prep v2 (R9, kept).
// ---------------------------------------------------------------------------
__global__ __launch_bounds__(256) void k_prep(
    const float* __restrict__ cfcU, const float* __restrict__ cfcS,
    const float* __restrict__ cfcV, const float* __restrict__ pjU,
    const float* __restrict__ pjS,  const float* __restrict__ pjV,
    f16* __restrict__ w1T, f16* __restrict__ v1,
    f16* __restrict__ w2T, f16* __restrict__ v2)
{
    __shared__ float tile[32][33];
    const int b = blockIdx.x, t = threadIdx.x;

    if (b < 320) {                       // V copies: 320*256*8 = 655360 elems
        int j = (b * 256 + t) * 8;
        const float* src; f16* dst;
        if (j < 524288) { src = cfcV + j;            dst = v1 + j; }
        else            { src = pjV + (j - 524288);  dst = v2 + (j - 524288); }
        float4 a0 = *(const float4*)src, a1 = *(const float4*)(src + 4);
        *(f16x8*)dst = cvt8(a0, a1);
        return;
    }

    // tiled transpose+scale: dst[r][d] = src[d][r] * S[r]
    const float* src; const float* S; f16* dst; int R, tb;
    if (b < 448) { src = cfcU; S = cfcS; dst = w1T; R = 1024; tb = b - 320; }
    else         { src = pjU;  S = pjS;  dst = w2T; R = 4096; tb = b - 448; }
    const int td = tb >> 2, tr = tb & 3;

    const int r0 = t >> 3, c0 = (t & 7) * 4;
    float4 v  = *(const float4*)(src + (size_t)(td * 32 + r0) * 128 + tr * 32 + c0);
    float4 sv = *(const float4*)(S + tr * 32 + c0);
    tile[r0][c0 + 0] = v.x * sv.x;
    tile[r0][c0 + 1] = v.y * sv.y;
    tile[r0][c0 + 2] = v.z * sv.z;
    tile[r0][c0 + 3] = v.w * sv.w;
    __syncthreads();

    const int j = t >> 3, i4 = (t & 7) * 4;
    f16x4 o = { (f16)tile[i4 + 0][j], (f16)tile[i4 + 1][j],
                (f16)tile[i4 + 2][j], (f16)tile[i4 + 3][j] };
    *(f16x4*)&dst[(size_t)(tr * 32 + j) * R + td * 32 + i4] = o;
}

// ---------------------------------------------------------------------------
// Stage 1 v3 (R9, kept).
// ---------------------------------------------------------------------------
__global__ __launch_bounds__(256, 2) void k_t1(
    const float* __restrict__ x, const f16* __restrict__ w1T,
    f16* __restrict__ t1p)
{
    __shared__ __align__(16) char w1s[65536];      // [128 r][512 B] linear

    const int tid  = threadIdx.x;
    const int lane = tid & 63;
    const int wv   = tid >> 6;
    const int wm   = wv & 1, wn = wv >> 1;
    const int m0b  = blockIdx.x * 32;
    const int h    = blockIdx.y;
    const int c    = lane & 15, q = lane >> 4;

#define STAGEW(kk)                                                              \
    _Pragma("unroll") for (int i = 0; i < 16; ++i) {                            \
        int r0_  = wv * 32 + i * 2;                                             \
        int row_ = r0_ + (lane >> 5);                                           \
        int col_ = ((lane & 31) * 16) ^ ((row_ & 7) << 4);                      \
        GLOAD16((const char*)w1T + (size_t)row_ * 2048 + h * 1024 +             \
                (kk) * 512 + col_,                                              \
                w1s + r0_ * 512);                                               \
    }

#define LOADX(dst, kc)                                                          \
    _Pragma("unroll") for (int kb = 0; kb < 4; ++kb) {                          \
        const float* px = &x[(size_t)(m0b + wm * 16 + c) * D_MODEL +            \
                             h * 512 + (kc) * 128 + kb * 32 + q * 8];           \
        dst[kb][0] = *(const float4*)px;                                        \
        dst[kb][1] = *(const float4*)(px + 4); }

#define COMPUTEKC(src, sc)                                                      \
    _Pragma("unroll") for (int kb = 0; kb < 4; ++kb) {                          \
        f16x8 af = cvt8(src[kb][0], src[kb][1]);                                \
        _Pragma("unroll") for (int nt = 0; nt < 4; ++nt) {                      \
            int row_ = wn * 64 + nt * 16 + c;                                   \
            f16x8 bf = *(const f16x8*)(w1s + row_ * 512 +                       \
                (((sc) * 256 + kb * 64 + q * 16) ^ ((row_ & 7) << 4)));         \
            acc[nt] = MFMA16(af, bf, acc[nt]); } }

    float4 xa[4][2], xb[4][2];
    LOADX(xa, 0)
    STAGEW(0)
    __syncthreads();

    f32x4 acc[4] = {};
    LOADX(xb, 1)
    COMPUTEKC(xa, 0)
    COMPUTEKC(xb, 1)
    __syncthreads();
    STAGEW(1)
    LOADX(xa, 2)
    __syncthreads();
    LOADX(xb, 3)
    COMPUTEKC(xa, 0)
    COMPUTEKC(xb, 1)

    f16* o = t1p + (size_t)h * (M_ROWS * RANK);
#pragma unroll
    for (int nt = 0; nt < 4; ++nt)
#pragma unroll
        for (int i2 = 0; i2 < 4; ++i2)
            o[(size_t)(m0b + wm * 16 + q * 4 + i2) * RANK + wn * 64 + nt * 16 + c] =
                (f16)acc[nt][i2];
#undef STAGEW
#undef LOADX
#undef COMPUTEKC
}

// ---------------------------------------------------------------------------
// Fused stages 2+3 v9: R8 pipeline (proven 51.5us) at 4 waves/SIMD.
// R9 PMC arithmetic: VALUBusy 43% @ 2 waves/SIMD, gelu serial between the
// two MFMA phases -> MFMA idles. v9: 512 thr = 8 waves (wm=wv&1 m-half,
// wf=wv>>1 f-QUARTER of 16 per 64-f tile), same grid 512, same LDS 72.7 KB
// -> 2 blocks/CU x 8 waves = 4 waves/SIMD. Per-thread regs SHRINK (c2[1]).
// Stage3 keeps the proven K=32 MFMA with zero-masked A: lanes whose k-slice
// (q>>1) != wave's sub-half (wf&1) contribute 0; the 4-way wf-reduce sums
// quarters. B-read pattern byte-identical to R8 (conflict-free proven).
// ---------------------------------------------------------------------------
#define V1OFF 0          // [2][64 f][256 B]  2*16384
#define W2OFF 32768      // [2][128 r][128 B] 2*16384
#define HSOFF 65536      // [8 waves][16 m][24 f16 = 48 B] 6144
#define HSTR  24

__global__ __launch_bounds__(512, 2) void k_fused(
    const f16* __restrict__ t1p, const f16* __restrict__ v1,
    const float* __restrict__ bfc, const f16* __restrict__ w2T,
    f16* __restrict__ t2p)
{
    __shared__ __align__(16) char smem[72704];

    const int tid  = threadIdx.x;
    const int lane = tid & 63;
    const int wv   = tid >> 6;                     // 0..7
    const int wm   = wv & 1, wf = wv >> 1;         // wf 0..3
    const int c    = lane & 15, q = lane >> 4;

    // XCD swizzle (bijective, 512 = 64*8): XCDs 0-3 -> s=0, 4-7 -> s=1
    const int bx  = blockIdx.x;
    const int s   = (bx & 7) >> 2;
    const int mb  = (bx >> 3) * 4 + (bx & 3);      // 0..255
    const int m0b = mb * 32;

    f16* hsw = (f16*)(smem + HSOFF + wv * (16 * HSTR * 2));

    // stage a 64-f tile: v1 [64f][256B], w2T [128r][128B]; 4 issues/thread
#define STAGE(bsel, itn) {                                                      \
    const int ft_ = s * 2048 + (itn) * 64;                                      \
    _Pragma("unroll") for (int i = 0; i < 2; ++i) {                             \
        int rb_  = wv * 8 + i * 4;                                              \
        int row_ = rb_ + (lane >> 4);                                           \
        int col_ = ((lane & 15) * 16) ^ ((row_ & 7) << 4);                      \
        GLOAD16((const char*)v1 + (size_t)(ft_ + row_) * 256 + col_,            \
                smem + V1OFF + (bsel) * 16384 + rb_ * 256);                     \
    }                                                                           \
    _Pragma("unroll") for (int i = 0; i < 2; ++i) {                             \
        int rb_  = wv * 16 + i * 8;                                             \
        int row_ = rb_ + (lane >> 3);                                           \
        int col_ = ((lane & 7) * 16) ^ ((row_ & 7) << 4);                       \
        GLOAD16((const char*)w2T + (size_t)row_ * 8192 + (size_t)ft_ * 2 + col_,\
                smem + W2OFF + (bsel) * 16384 + rb_ * 128);                     \
    }                                                                           \
}

    // A2 fragments: f16 sum of the two t1 partials (proven)
    f16x8 a2[4];
#pragma unroll
    for (int kb = 0; kb < 4; ++kb) {
        const size_t off = (size_t)(m0b + wm * 16 + c) * RANK + kb * 32 + q * 8;
        f16x8 p0 = ld8(t1p + off);
        f16x8 p1 = ld8(t1p + (size_t)(M_ROWS * RANK) + off);
#pragma unroll
        for (int e = 0; e < 8; ++e)
            a2[kb][e] = (f16)((float)p0[e] + (float)p1[e]);
    }

    STAGE(0, 0)
    __syncthreads();                               // buf0 landed

    f32x4 c3[8] = {};
    const f16x8 zf = {};
    const bool aact = (q >> 1) == (wf & 1);        // stage3 A-mask for this lane

#pragma unroll 1
    for (int it = 0; it < 32; ++it) {
        const int cur = it & 1;
        const int ft  = s * 2048 + it * 64;

        float bb = bfc[ft + wf * 16 + c];

        if (it < 31) STAGE(cur ^ 1, it + 1)        // prefetch next tile

        // ---- stage 2: h[16m][16f quarter] = t1 @ v1^T (4 MFMA)
        f32x4 c2 = {};
#pragma unroll
        for (int kb = 0; kb < 4; ++kb) {
            int row = wf * 16 + c;
            f16x8 bv = *(const f16x8*)(smem + V1OFF + cur * 16384 +
                row * 256 + ((kb * 64 + q * 16) ^ ((row & 7) << 4)));
            c2 = MFMA16(a2[kb], bv, c2);
        }

        // ---- bias + gelu -> per-wave hs [16m][24 f16]
#pragma unroll
        for (int i2 = 0; i2 < 4; ++i2)
            hsw[(q * 4 + i2) * HSTR + c] = (f16)gelu_fast(c2[i2] + bb);
        asm volatile("s_waitcnt lgkmcnt(0)" ::: "memory"); // cross-lane RAW

        // ---- stage 3: c3 += h @ w2T^T over the wf-pair's 32-f K-block;
        //      A zero-masked to this wave's 16-f quarter.
        f16x8 h8 = *(const f16x8*)(hsw + c * HSTR + (q & 1) * 8);
        f16x8 a3 = aact ? h8 : zf;
#pragma unroll
        for (int rt = 0; rt < 8; ++rt) {
            int rr = rt * 16 + c;
            f16x8 bw = *(const f16x8*)(smem + W2OFF + cur * 16384 +
                rr * 128 + (((wf >> 1) * 64 + q * 16) ^ ((rr & 7) << 4)));
            c3[rt] = MFMA16(a3, bw, c3[rt]);
        }
        asm volatile("s_waitcnt lgkmcnt(0)" ::: "memory"); // WAR on hs

        __syncthreads();   // next-tile loads landed + hs/tiles safe
    }
#undef STAGE

    // ---- epilogue: 4-way wf-reduce per wm (tree), write f16 t2p[s]
    float* rbuf = (float*)smem;                    // 4 regions of [16][132] f32

#define ST_C3(rg)                                                               \
    { float* rb = rbuf + (rg) * 2112;                                           \
      _Pragma("unroll") for (int rt = 0; rt < 8; ++rt)                          \
      _Pragma("unroll") for (int i2 = 0; i2 < 4; ++i2)                          \
          rb[(q * 4 + i2) * 132 + rt * 16 + c] = c3[rt][i2]; }
#define ADD_C3(rg)                                                              \
    { float* rb = rbuf + (rg) * 2112;                                           \
      _Pragma("unroll") for (int rt = 0; rt < 8; ++rt)                          \
      _Pragma("unroll") for (int i2 = 0; i2 < 4; ++i2)                          \
          c3[rt][i2] += rb[(q * 4 + i2) * 132 + rt * 16 + c]; }

    __syncthreads();                               // all waves done with hs
    if (wf >= 2) ST_C3(wm * 2 + (wf - 2))
    __syncthreads();
    if (wf < 2) ADD_C3(wm * 2 + wf)
    __syncthreads();
    if (wf == 1) ST_C3(wm * 2)
    __syncthreads();
    if (wf == 0) {
        ADD_C3(wm * 2)
        f16* o = t2p + (size_t)s * (M_ROWS * RANK);
#pragma unroll
        for (int rt = 0; rt < 8; ++rt)
#pragma unroll
            for (int i2 = 0; i2 < 4; ++i2)
                o[(size_t)(m0b + wm * 16 + q * 4 + i2) * RANK + rt * 16 + c] =
                    (f16)c3[rt][i2];
    }
#undef ST_C3
#undef ADD_C3
}

// ---------------------------------------------------------------------------
// Stage 4 v2 (R9, kept).
// ---------------------------------------------------------------------------
__global__ __launch_bounds__(512, 2) void k_out(
    const f16* __restrict__ t2p, const f16* __restrict__ v2,
    const float* __restrict__ bpj, float* __restrict__ out)
{
    __shared__ __align__(16) f16 v2s[256 * 136];

    const int tid  = threadIdx.x;
    const int lane = tid & 63;
    const int wv   = tid >> 6;
    const int wm   = wv & 3, wn = wv >> 2;
    const int m0b  = blockIdx.x * 64;
    const int n0b  = blockIdx.y * 256;
    const int c    = lane & 15, q = lane >> 4;

#pragma unroll
    for (int i8 = 0; i8 < 8; ++i8) {
        int id = i8 * 512 + tid;
        int nn = id >> 4, k8 = id & 15;
        *(f16x8*)&v2s[nn * 136 + k8 * 8] =
            ld8(v2 + (size_t)(n0b + nn) * RANK + k8 * 8);
    }

    f16x8 a[4];
#pragma unroll
    for (int kb = 0; kb < 4; ++kb) {
        const size_t off = (size_t)(m0b + wm * 16 + c) * RANK + kb * 32 + q * 8;
        f16x8 p0 = ld8(t2p + off);
        f16x8 p1 = ld8(t2p + (size_t)(M_ROWS * RANK) + off);
#pragma unroll
        for (int e = 0; e < 8; ++e)
            a[kb][e] = (f16)((float)p0[e] + (float)p1[e]);
    }
    __syncthreads();

    f32x4 acc[8] = {};
#pragma unroll
    for (int nt = 0; nt < 8; ++nt)
#pragma unroll
        for (int kb = 0; kb < 4; ++kb) {
            f16x8 bf = *(const f16x8*)
                &v2s[(wn * 128 + nt * 16 + c) * 136 + kb * 32 + q * 8];
            acc[nt] = MFMA16(a[kb], bf, acc[nt]);
        }

#pragma unroll
    for (int nt = 0; nt < 8; ++nt) {
        float b = bpj[n0b + wn * 128 + nt * 16 + c];
#pragma unroll
        for (int i2 = 0; i2 < 4; ++i2)
            out[(size_t)(m0b + wm * 16 + q * 4 + i2) * D_MODEL +
                n0b + wn * 128 + nt * 16 + c] = acc[nt][i2] + b;
    }
}

extern "C" void kernel_launch(void* const* d_in, const int* in_sizes, int n_in,
                              void* d_out, int out_size, void* d_ws, size_t ws_size,
                              hipStream_t stream) {
    const float* x    = (const float*)d_in[0];
    const float* cfcU = (const float*)d_in[1];
    const float* cfcS = (const float*)d_in[2];
    const float* cfcV = (const float*)d_in[3];
    const float* cfcB = (const float*)d_in[4];
    const float* pjU  = (const float*)d_in[5];
    const float* pjS  = (const float*)d_in[6];
    const float* pjV  = (const float*)d_in[7];
    const float* pjB  = (const float*)d_in[8];
    float* out = (float*)d_out;

    // ws layout (f16 elements), 10.5 MB (12 MB proven safe):
    f16* wsf = (f16*)d_ws;
    f16* t1p = wsf;                 // [2][8192*128]  4 MB
    f16* t2p = wsf + 2097152;       // [2][8192*128]  4 MB
    f16* w1T = wsf + 4194304;       // [128*1024]
    f16* v1  = w1T + 131072;        // [4096*128]
    f16* w2T = v1  + 524288;        // [128*4096]
    f16* v2  = w2T + 524288;        // [1024*128]

    k_prep <<<dim3(960), 256, 0, stream>>>(cfcU, cfcS, cfcV, pjU, pjS, pjV,
                                           w1T, v1, w2T, v2);
    k_t1   <<<dim3(M_ROWS / 32, 2), 256, 0, stream>>>(x, w1T, t1p);
    k_fused<<<dim3(512), 512, 0, stream>>>(t1p, v1, cfcB, w2T, t2p);
    k_out  <<<dim3(M_ROWS / 64, D_MODEL / 256), 512, 0, stream>>>(t2p, v2, pjB, out);
}

// Round 11
// 167.073 us; speedup vs baseline: 1.0121x; 1.0121x over previous
//
#include <hip/hip_runtime.h>
#include <math.h>

#define D_MODEL 1024
#define D_FF    4096
#define RANK    128
#define M_ROWS  8192

typedef _Float16 f16;
typedef _Float16 f16x8 __attribute__((ext_vector_type(8)));
typedef _Float16 f16x4 __attribute__((ext_vector_type(4)));
typedef float    f32x4 __attribute__((ext_vector_type(4)));

#define MFMA16(a, b, c) __builtin_amdgcn_mfma_f32_16x16x32_f16((a), (b), (c), 0, 0, 0)

__device__ __forceinline__ f16x8 ld8(const f16* p) { return *(const f16x8*)p; }

__device__ __forceinline__ f16x8 cvt8(float4 a0, float4 a1) {
    f16x8 r = { (f16)a0.x, (f16)a0.y, (f16)a0.z, (f16)a0.w,
                (f16)a1.x, (f16)a1.y, (f16)a1.z, (f16)a1.w };
    return r;
}

// Fast exact-gelu (proven R2/R4/R8, absmax 9.77e-4).
__device__ __forceinline__ float gelu_fast(float v) {
    float u  = v * 0.70710678118654752440f;
    float au = fabsf(u);
    float t  = __builtin_amdgcn_rcpf(__builtin_fmaf(0.3275911f, au, 1.0f));
    float e  = __expf(-au * au);
    float p  = __builtin_fmaf(1.061405429f, t, -1.453152027f);
    p = __builtin_fmaf(p, t, 1.421413741f);
    p = __builtin_fmaf(p, t, -0.284496736f);
    p = __builtin_fmaf(p, t, 0.254829592f);
    float er = __builtin_fmaf(-p * t, e, 1.0f);
    er = copysignf(er, u);
    return 0.5f * v * (1.0f + er);
}

// async global->LDS, 16 B per lane; LDS dest wave-uniform base + lane*16
#define GLOAD16(gp, lp) __builtin_amdgcn_global_load_lds(                     \
    (const __attribute__((address_space(1))) void*)(gp),                      \
    (__attribute__((address_space(3))) void*)(lp), 16, 0, 0)

// ---------------------------------------------------------------------------
// Prep v2 (R9, kept).
// ---------------------------------------------------------------------------
__global__ __launch_bounds__(256) void k_prep(
    const float* __restrict__ cfcU, const float* __restrict__ cfcS,
    const float* __restrict__ cfcV, const float* __restrict__ pjU,
    const float* __restrict__ pjS,  const float* __restrict__ pjV,
    f16* __restrict__ w1T, f16* __restrict__ v1,
    f16* __restrict__ w2T, f16* __restrict__ v2)
{
    __shared__ float tile[32][33];
    const int b = blockIdx.x, t = threadIdx.x;

    if (b < 320) {                       // V copies: 320*256*8 = 655360 elems
        int j = (b * 256 + t) * 8;
        const float* src; f16* dst;
        if (j < 524288) { src = cfcV + j;            dst = v1 + j; }
        else            { src = pjV + (j - 524288);  dst = v2 + (j - 524288); }
        float4 a0 = *(const float4*)src, a1 = *(const float4*)(src + 4);
        *(f16x8*)dst = cvt8(a0, a1);
        return;
    }

    // tiled transpose+scale: dst[r][d] = src[d][r] * S[r]
    const float* src; const float* S; f16* dst; int R, tb;
    if (b < 448) { src = cfcU; S = cfcS; dst = w1T; R = 1024; tb = b - 320; }
    else         { src = pjU;  S = pjS;  dst = w2T; R = 4096; tb = b - 448; }
    const int td = tb >> 2, tr = tb & 3;

    const int r0 = t >> 3, c0 = (t & 7) * 4;
    float4 v  = *(const float4*)(src + (size_t)(td * 32 + r0) * 128 + tr * 32 + c0);
    float4 sv = *(const float4*)(S + tr * 32 + c0);
    tile[r0][c0 + 0] = v.x * sv.x;
    tile[r0][c0 + 1] = v.y * sv.y;
    tile[r0][c0 + 2] = v.z * sv.z;
    tile[r0][c0 + 3] = v.w * sv.w;
    __syncthreads();

    const int j = t >> 3, i4 = (t & 7) * 4;
    f16x4 o = { (f16)tile[i4 + 0][j], (f16)tile[i4 + 1][j],
                (f16)tile[i4 + 2][j], (f16)tile[i4 + 3][j] };
    *(f16x4*)&dst[(size_t)(tr * 32 + j) * R + td * 32 + i4] = o;
}

// ---------------------------------------------------------------------------
// Stage 1 v3 (R9, kept).
// ---------------------------------------------------------------------------
__global__ __launch_bounds__(256, 2) void k_t1(
    const float* __restrict__ x, const f16* __restrict__ w1T,
    f16* __restrict__ t1p)
{
    __shared__ __align__(16) char w1s[65536];      // [128 r][512 B] linear

    const int tid  = threadIdx.x;
    const int lane = tid & 63;
    const int wv   = tid >> 6;
    const int wm   = wv & 1, wn = wv >> 1;
    const int m0b  = blockIdx.x * 32;
    const int h    = blockIdx.y;
    const int c    = lane & 15, q = lane >> 4;

#define STAGEW(kk)                                                              \
    _Pragma("unroll") for (int i = 0; i < 16; ++i) {                            \
        int r0_  = wv * 32 + i * 2;                                             \
        int row_ = r0_ + (lane >> 5);                                           \
        int col_ = ((lane & 31) * 16) ^ ((row_ & 7) << 4);                      \
        GLOAD16((const char*)w1T + (size_t)row_ * 2048 + h * 1024 +             \
                (kk) * 512 + col_,                                              \
                w1s + r0_ * 512);                                               \
    }

#define LOADX(dst, kc)                                                          \
    _Pragma("unroll") for (int kb = 0; kb < 4; ++kb) {                          \
        const float* px = &x[(size_t)(m0b + wm * 16 + c) * D_MODEL +            \
                             h * 512 + (kc) * 128 + kb * 32 + q * 8];           \
        dst[kb][0] = *(const float4*)px;                                        \
        dst[kb][1] = *(const float4*)(px + 4); }

#define COMPUTEKC(src, sc)                                                      \
    _Pragma("unroll") for (int kb = 0; kb < 4; ++kb) {                          \
        f16x8 af = cvt8(src[kb][0], src[kb][1]);                                \
        _Pragma("unroll") for (int nt = 0; nt < 4; ++nt) {                      \
            int row_ = wn * 64 + nt * 16 + c;                                   \
            f16x8 bf = *(const f16x8*)(w1s + row_ * 512 +                       \
                (((sc) * 256 + kb * 64 + q * 16) ^ ((row_ & 7) << 4)));         \
            acc[nt] = MFMA16(af, bf, acc[nt]); } }

    float4 xa[4][2], xb[4][2];
    LOADX(xa, 0)
    STAGEW(0)
    __syncthreads();

    f32x4 acc[4] = {};
    LOADX(xb, 1)
    COMPUTEKC(xa, 0)
    COMPUTEKC(xb, 1)
    __syncthreads();
    STAGEW(1)
    LOADX(xa, 2)
    __syncthreads();
    LOADX(xb, 3)
    COMPUTEKC(xa, 0)
    COMPUTEKC(xb, 1)

    f16* o = t1p + (size_t)h * (M_ROWS * RANK);
#pragma unroll
    for (int nt = 0; nt < 4; ++nt)
#pragma unroll
        for (int i2 = 0; i2 < 4; ++i2)
            o[(size_t)(m0b + wm * 16 + q * 4 + i2) * RANK + wn * 64 + nt * 16 + c] =
                (f16)acc[nt][i2];
#undef STAGEW
#undef LOADX
#undef COMPUTEKC
}

// ---------------------------------------------------------------------------
// Fused stages 2+3 v8r (R8-proven 51.5us, reverted from v9's regression):
// R10 post-mortem: the wf-quarter split doubled stage-3 MFMA count via
// zero-masked A (useful-op throughput halved) — occupancy was never the
// binding constraint. v8r = v8 verbatim EXCEPT the v1-tile swizzle widened
// from (row&7)<<4 to (row&15)<<4 (256-B rows have 16 16-B slots; bijective,
// correctness-invariant by the gload symmetry LDS(row,x)=G(row,x^s(row))).
// Stage-2 read rows satisfy row&15 == c, so 16 c-lanes now spread over 16
// slots instead of 8 -> that conflict class halves. w2s (128-B rows) keeps
// &7 (structural 3-bit cap).
// ---------------------------------------------------------------------------
#define V1OFF 0          // [2][64 f][256 B]  2*16384
#define W2OFF 32768      // [2][128 r][128 B] 2*16384
#define HSOFF 65536      // [4 waves][16 m][56 f16 = 112 B] 7168
#define HSTR  56

__global__ __launch_bounds__(256, 2) void k_fused(
    const f16* __restrict__ t1p, const f16* __restrict__ v1,
    const float* __restrict__ bfc, const f16* __restrict__ w2T,
    f16* __restrict__ t2p)
{
    __shared__ __align__(16) char smem[72704];

    const int tid  = threadIdx.x;
    const int lane = tid & 63;
    const int wv   = tid >> 6;                     // 0..3
    const int wm   = wv & 1, wf = wv >> 1;
    const int c    = lane & 15, q = lane >> 4;

    // XCD swizzle (bijective, 512 = 64*8): XCDs 0-3 -> s=0, 4-7 -> s=1
    const int bx  = blockIdx.x;
    const int s   = (bx & 7) >> 2;
    const int mb  = (bx >> 3) * 4 + (bx & 3);      // 0..255
    const int m0b = mb * 32;
    const int fw  = wf * 32;                       // wave's f-slice in 64-f tile

    f16* hsw = (f16*)(smem + HSOFF + wv * (16 * HSTR * 2));

#define STAGE(bsel, itn) {                                                      \
    const int ft_ = s * 2048 + (itn) * 64;                                      \
    _Pragma("unroll") for (int i = 0; i < 4; ++i) {                             \
        int rb_  = wv * 16 + i * 4;                                             \
        int row_ = rb_ + (lane >> 4);                                           \
        int col_ = ((lane & 15) * 16) ^ ((row_ & 15) << 4);                     \
        GLOAD16((const char*)v1 + (size_t)(ft_ + row_) * 256 + col_,            \
                smem + V1OFF + (bsel) * 16384 + rb_ * 256);                     \
    }                                                                           \
    _Pragma("unroll") for (int i = 0; i < 4; ++i) {                             \
        int rb_  = wv * 32 + i * 8;                                             \
        int row_ = rb_ + (lane >> 3);                                           \
        int col_ = ((lane & 7) * 16) ^ ((row_ & 7) << 4);                       \
        GLOAD16((const char*)w2T + (size_t)row_ * 8192 + (size_t)ft_ * 2 + col_,\
                smem + W2OFF + (bsel) * 16384 + rb_ * 128);                     \
    }                                                                           \
}

    // A2 fragments: f16 sum of the two t1 partials (proven)
    f16x8 a2[4];
#pragma unroll
    for (int kb = 0; kb < 4; ++kb) {
        const size_t off = (size_t)(m0b + wm * 16 + c) * RANK + kb * 32 + q * 8;
        f16x8 p0 = ld8(t1p + off);
        f16x8 p1 = ld8(t1p + (size_t)(M_ROWS * RANK) + off);
#pragma unroll
        for (int e = 0; e < 8; ++e)
            a2[kb][e] = (f16)((float)p0[e] + (float)p1[e]);
    }

    STAGE(0, 0)
    __syncthreads();                               // buf0 landed (vmcnt drain)

    f32x4 c3[8] = {};

#pragma unroll 1
    for (int it = 0; it < 32; ++it) {
        const int cur = it & 1;
        const int ft  = s * 2048 + it * 64;

        float bb[2];
        bb[0] = bfc[ft + fw + c];
        bb[1] = bfc[ft + fw + 16 + c];

        if (it < 31) STAGE(cur ^ 1, it + 1)        // prefetch next tile

        // ---- stage 2: h[16m][32f] = t1 @ v1^T (2 nt x 4 kb MFMA)
        f32x4 c2[2] = {};
#pragma unroll
        for (int nt = 0; nt < 2; ++nt)
#pragma unroll
            for (int kb = 0; kb < 4; ++kb) {
                int row = fw + nt * 16 + c;
                f16x8 bv = *(const f16x8*)(smem + V1OFF + cur * 16384 +
                    row * 256 + ((kb * 64 + q * 16) ^ ((row & 15) << 4)));
                c2[nt] = MFMA16(a2[kb], bv, c2[nt]);
            }

        // ---- bias + gelu -> per-wave hs [16][HSTR]
#pragma unroll
        for (int nt = 0; nt < 2; ++nt)
#pragma unroll
            for (int i2 = 0; i2 < 4; ++i2)
                hsw[(q * 4 + i2) * HSTR + nt * 16 + c] =
                    (f16)gelu_fast(c2[nt][i2] + bb[nt]);
        asm volatile("s_waitcnt lgkmcnt(0)" ::: "memory"); // cross-lane RAW

        // ---- stage 3: c3 += h @ w2T^T (K=32, 8 rt MFMA)
        f16x8 a3 = *(const f16x8*)(hsw + c * HSTR + q * 8);
#pragma unroll
        for (int rt = 0; rt < 8; ++rt) {
            int rr = rt * 16 + c;
            f16x8 bw = *(const f16x8*)(smem + W2OFF + cur * 16384 +
                rr * 128 + ((wf * 64 + q * 16) ^ ((c & 7) << 4)));
            c3[rt] = MFMA16(a3, bw, c3[rt]);
        }
        asm volatile("s_waitcnt lgkmcnt(0)" ::: "memory"); // WAR on hs

        __syncthreads();   // next-tile loads landed + hs/tiles safe
    }
#undef STAGE

    // ---- epilogue: 2-wave reduce over wf (proven), write f16 t2p[s]
    float* rbuf = (float*)smem;

    if (wf == 1) {
        float* rb = rbuf + wm * 2112;
#pragma unroll
        for (int rt = 0; rt < 8; ++rt)
#pragma unroll
            for (int i2 = 0; i2 < 4; ++i2)
                rb[(q * 4 + i2) * 132 + rt * 16 + c] = c3[rt][i2];
    }
    __syncthreads();
    if (wf == 0) {
        float* rb = rbuf + wm * 2112;
#pragma unroll
        for (int rt = 0; rt < 8; ++rt)
#pragma unroll
            for (int i2 = 0; i2 < 4; ++i2)
                c3[rt][i2] += rb[(q * 4 + i2) * 132 + rt * 16 + c];
        f16* o = t2p + (size_t)s * (M_ROWS * RANK);
#pragma unroll
        for (int rt = 0; rt < 8; ++rt)
#pragma unroll
            for (int i2 = 0; i2 < 4; ++i2)
                o[(size_t)(m0b + wm * 16 + q * 4 + i2) * RANK + rt * 16 + c] =
                    (f16)c3[rt][i2];
    }
}

// ---------------------------------------------------------------------------
// Stage 4 v2 (R9, kept).
// ---------------------------------------------------------------------------
__global__ __launch_bounds__(512, 2) void k_out(
    const f16* __restrict__ t2p, const f16* __restrict__ v2,
    const float* __restrict__ bpj, float* __restrict__ out)
{
    __shared__ __align__(16) f16 v2s[256 * 136];

    const int tid  = threadIdx.x;
    const int lane = tid & 63;
    const int wv   = tid >> 6;
    const int wm   = wv & 3, wn = wv >> 2;
    const int m0b  = blockIdx.x * 64;
    const int n0b  = blockIdx.y * 256;
    const int c    = lane & 15, q = lane >> 4;

#pragma unroll
    for (int i8 = 0; i8 < 8; ++i8) {
        int id = i8 * 512 + tid;
        int nn = id >> 4, k8 = id & 15;
        *(f16x8*)&v2s[nn * 136 + k8 * 8] =
            ld8(v2 + (size_t)(n0b + nn) * RANK + k8 * 8);
    }

    f16x8 a[4];
#pragma unroll
    for (int kb = 0; kb < 4; ++kb) {
        const size_t off = (size_t)(m0b + wm * 16 + c) * RANK + kb * 32 + q * 8;
        f16x8 p0 = ld8(t2p + off);
        f16x8 p1 = ld8(t2p + (size_t)(M_ROWS * RANK) + off);
#pragma unroll
        for (int e = 0; e < 8; ++e)
            a[kb][e] = (f16)((float)p0[e] + (float)p1[e]);
    }
    __syncthreads();

    f32x4 acc[8] = {};
#pragma unroll
    for (int nt = 0; nt < 8; ++nt)
#pragma unroll
        for (int kb = 0; kb < 4; ++kb) {
            f16x8 bf = *(const f16x8*)
                &v2s[(wn * 128 + nt * 16 + c) * 136 + kb * 32 + q * 8];
            acc[nt] = MFMA16(a[kb], bf, acc[nt]);
        }

#pragma unroll
    for (int nt = 0; nt < 8; ++nt) {
        float b = bpj[n0b + wn * 128 + nt * 16 + c];
#pragma unroll
        for (int i2 = 0; i2 < 4; ++i2)
            out[(size_t)(m0b + wm * 16 + q * 4 + i2) * D_MODEL +
                n0b + wn * 128 + nt * 16 + c] = acc[nt][i2] + b;
    }
}

extern "C" void kernel_launch(void* const* d_in, const int* in_sizes, int n_in,
                              void* d_out, int out_size, void* d_ws, size_t ws_size,
                              hipStream_t stream) {
    const float* x    = (const float*)d_in[0];
    const float* cfcU = (const float*)d_in[1];
    const float* cfcS = (const float*)d_in[2];
    const float* cfcV = (const float*)d_in[3];
    const float* cfcB = (const float*)d_in[4];
    const float* pjU  = (const float*)d_in[5];
    const float* pjS  = (const float*)d_in[6];
    const float* pjV  = (const float*)d_in[7];
    const float* pjB  = (const float*)d_in[8];
    float* out = (float*)d_out;

    // ws layout (f16 elements), 10.5 MB (12 MB proven safe):
    f16* wsf = (f16*)d_ws;
    f16* t1p = wsf;                 // [2][8192*128]  4 MB
    f16* t2p = wsf + 2097152;       // [2][8192*128]  4 MB
    f16* w1T = wsf + 4194304;       // [128*1024]
    f16* v1  = w1T + 131072;        // [4096*128]
    f16* w2T = v1  + 524288;        // [128*4096]
    f16* v2  = w2T + 524288;        // [1024*128]

    k_prep <<<dim3(960), 256, 0, stream>>>(cfcU, cfcS, cfcV, pjU, pjS, pjV,
                                           w1T, v1, w2T, v2);
    k_t1   <<<dim3(M_ROWS / 32, 2), 256, 0, stream>>>(x, w1T, t1p);
    k_fused<<<dim3(512), 256, 0, stream>>>(t1p, v1, cfcB, w2T, t2p);
    k_out  <<<dim3(M_ROWS / 64, D_MODEL / 256), 512, 0, stream>>>(t2p, v2, pjB, out);
}

// Round 12
// 166.625 us; speedup vs baseline: 1.0148x; 1.0027x over previous
//
#include <hip/hip_runtime.h>
#include <math.h>

#define D_MODEL 1024
#define D_FF    4096
#define RANK    128
#define M_ROWS  8192

typedef _Float16 f16;
typedef _Float16 f16x8 __attribute__((ext_vector_type(8)));
typedef _Float16 f16x4 __attribute__((ext_vector_type(4)));
typedef float    f32x4 __attribute__((ext_vector_type(4)));

#define MFMA16(a, b, c) __builtin_amdgcn_mfma_f32_16x16x32_f16((a), (b), (c), 0, 0, 0)

__device__ __forceinline__ f16x8 ld8(const f16* p) { return *(const f16x8*)p; }

__device__ __forceinline__ f16x8 cvt8(float4 a0, float4 a1) {
    f16x8 r = { (f16)a0.x, (f16)a0.y, (f16)a0.z, (f16)a0.w,
                (f16)a1.x, (f16)a1.y, (f16)a1.z, (f16)a1.w };
    return r;
}

// Fast exact-gelu (proven R2/R4/R8, absmax 9.77e-4).
__device__ __forceinline__ float gelu_fast(float v) {
    float u  = v * 0.70710678118654752440f;
    float au = fabsf(u);
    float t  = __builtin_amdgcn_rcpf(__builtin_fmaf(0.3275911f, au, 1.0f));
    float e  = __expf(-au * au);
    float p  = __builtin_fmaf(1.061405429f, t, -1.453152027f);
    p = __builtin_fmaf(p, t, 1.421413741f);
    p = __builtin_fmaf(p, t, -0.284496736f);
    p = __builtin_fmaf(p, t, 0.254829592f);
    float er = __builtin_fmaf(-p * t, e, 1.0f);
    er = copysignf(er, u);
    return 0.5f * v * (1.0f + er);
}

// async global->LDS, 16 B per lane; LDS dest wave-uniform base + lane*16
#define GLOAD16(gp, lp) __builtin_amdgcn_global_load_lds(                     \
    (const __attribute__((address_space(1))) void*)(gp),                      \
    (__attribute__((address_space(3))) void*)(lp), 16, 0, 0)

// ---------------------------------------------------------------------------
// Prep (R1-set revert: best measured residual 95.6/96.4 us in R1/R7).
// Scalar but massively parallel (5120 blocks).
// ---------------------------------------------------------------------------
__global__ __launch_bounds__(256) void k_prep(
    const float* __restrict__ cfcU, const float* __restrict__ cfcS,
    const float* __restrict__ cfcV, const float* __restrict__ pjU,
    const float* __restrict__ pjS,  const float* __restrict__ pjV,
    f16* __restrict__ w1T, f16* __restrict__ v1,
    f16* __restrict__ w2T, f16* __restrict__ v2)
{
    int i = blockIdx.x * 256 + threadIdx.x;
    if (i < 131072) {
        int r = i >> 10, d = i & 1023;
        w1T[i] = (f16)(cfcU[d * RANK + r] * cfcS[r]);
    } else if (i < 655360) {
        int j = i - 131072;
        v1[j] = (f16)cfcV[j];
    } else if (i < 1179648) {
        int j = i - 655360;
        int r = j >> 12, f = j & 4095;
        w2T[j] = (f16)(pjU[f * RANK + r] * pjS[r]);
    } else if (i < 1310720) {
        int j = i - 1179648;
        v2[j] = (f16)pjV[j];
    }
}

// ---------------------------------------------------------------------------
// Stage 1 (R1-set revert, proven): t1p[h][m][r] = x[m][K-half h] @ w1T^T.
// 512 thr, w1T K-half staged once (133 KB LDS), x reg-pipelined.
// ---------------------------------------------------------------------------
__global__ __launch_bounds__(512, 2) void k_t1(
    const float* __restrict__ x, const f16* __restrict__ w1T,
    f16* __restrict__ t1p)
{
    __shared__ __align__(16) f16 w1s[128 * 520];   // 133120 B

    const int tid  = threadIdx.x;
    const int lane = tid & 63;
    const int wv   = tid >> 6;
    const int wm   = wv & 3, wn = wv >> 2;
    const int m0b  = blockIdx.x * 64;
    const int h    = blockIdx.y;
    const int c    = lane & 15, q = lane >> 4;

#define LOADX(dst, kc)                                                          \
    _Pragma("unroll") for (int kb = 0; kb < 4; ++kb) {                          \
        const float* px = &x[(size_t)(m0b + wm * 16 + c) * D_MODEL +            \
                             h * 512 + (kc) * 128 + kb * 32 + q * 8];           \
        dst[kb][0] = *(const float4*)px;                                        \
        dst[kb][1] = *(const float4*)(px + 4); }

#define COMPUTEKC(src, kc)                                                      \
    _Pragma("unroll") for (int kb = 0; kb < 4; ++kb) {                          \
        f16x8 af = cvt8(src[kb][0], src[kb][1]);                                \
        _Pragma("unroll") for (int nt = 0; nt < 4; ++nt) {                      \
            f16x8 bf = *(const f16x8*)                                          \
                &w1s[(wn * 64 + nt * 16 + c) * 520 + (kc) * 128 + kb * 32 + q * 8]; \
            acc[nt] = MFMA16(af, bf, acc[nt]); } }

    float4 xa[4][2], xb[4][2];
    LOADX(xa, 0)

#pragma unroll
    for (int i = 0; i < 16; ++i) {
        int id = i * 512 + tid;
        int rr = id >> 6, k8 = id & 63;
        *(f16x8*)&w1s[rr * 520 + k8 * 8] =
            ld8(w1T + (size_t)rr * D_MODEL + h * 512 + k8 * 8);
    }
    __syncthreads();

    f32x4 acc[4] = {};
    LOADX(xb, 1)
    COMPUTEKC(xa, 0)
    LOADX(xa, 2)
    COMPUTEKC(xb, 1)
    LOADX(xb, 3)
    COMPUTEKC(xa, 2)
    COMPUTEKC(xb, 3)

    f16* o = t1p + (size_t)h * (M_ROWS * RANK);
#pragma unroll
    for (int nt = 0; nt < 4; ++nt)
#pragma unroll
        for (int i2 = 0; i2 < 4; ++i2)
            o[(size_t)(m0b + wm * 16 + q * 4 + i2) * RANK + wn * 64 + nt * 16 + c] =
                (f16)acc[nt][i2];
#undef LOADX
#undef COMPUTEKC
}

// ---------------------------------------------------------------------------
// Fused stages 2+3 v8r (R11, kept byte-identical: 51.6-52 us, conflicts 262K).
// ---------------------------------------------------------------------------
#define V1OFF 0          // [2][64 f][256 B]  2*16384
#define W2OFF 32768      // [2][128 r][128 B] 2*16384
#define HSOFF 65536      // [4 waves][16 m][56 f16 = 112 B] 7168
#define HSTR  56

__global__ __launch_bounds__(256, 2) void k_fused(
    const f16* __restrict__ t1p, const f16* __restrict__ v1,
    const float* __restrict__ bfc, const f16* __restrict__ w2T,
    f16* __restrict__ t2p)
{
    __shared__ __align__(16) char smem[72704];

    const int tid  = threadIdx.x;
    const int lane = tid & 63;
    const int wv   = tid >> 6;                     // 0..3
    const int wm   = wv & 1, wf = wv >> 1;
    const int c    = lane & 15, q = lane >> 4;

    // XCD swizzle (bijective, 512 = 64*8): XCDs 0-3 -> s=0, 4-7 -> s=1
    const int bx  = blockIdx.x;
    const int s   = (bx & 7) >> 2;
    const int mb  = (bx >> 3) * 4 + (bx & 3);      // 0..255
    const int m0b = mb * 32;
    const int fw  = wf * 32;                       // wave's f-slice in 64-f tile

    f16* hsw = (f16*)(smem + HSOFF + wv * (16 * HSTR * 2));

#define STAGE(bsel, itn) {                                                      \
    const int ft_ = s * 2048 + (itn) * 64;                                      \
    _Pragma("unroll") for (int i = 0; i < 4; ++i) {                             \
        int rb_  = wv * 16 + i * 4;                                             \
        int row_ = rb_ + (lane >> 4);                                           \
        int col_ = ((lane & 15) * 16) ^ ((row_ & 15) << 4);                     \
        GLOAD16((const char*)v1 + (size_t)(ft_ + row_) * 256 + col_,            \
                smem + V1OFF + (bsel) * 16384 + rb_ * 256);                     \
    }                                                                           \
    _Pragma("unroll") for (int i = 0; i < 4; ++i) {                             \
        int rb_  = wv * 32 + i * 8;                                             \
        int row_ = rb_ + (lane >> 3);                                           \
        int col_ = ((lane & 7) * 16) ^ ((row_ & 7) << 4);                       \
        GLOAD16((const char*)w2T + (size_t)row_ * 8192 + (size_t)ft_ * 2 + col_,\
                smem + W2OFF + (bsel) * 16384 + rb_ * 128);                     \
    }                                                                           \
}

    // A2 fragments: f16 sum of the two t1 partials (proven)
    f16x8 a2[4];
#pragma unroll
    for (int kb = 0; kb < 4; ++kb) {
        const size_t off = (size_t)(m0b + wm * 16 + c) * RANK + kb * 32 + q * 8;
        f16x8 p0 = ld8(t1p + off);
        f16x8 p1 = ld8(t1p + (size_t)(M_ROWS * RANK) + off);
#pragma unroll
        for (int e = 0; e < 8; ++e)
            a2[kb][e] = (f16)((float)p0[e] + (float)p1[e]);
    }

    STAGE(0, 0)
    __syncthreads();                               // buf0 landed (vmcnt drain)

    f32x4 c3[8] = {};

#pragma unroll 1
    for (int it = 0; it < 32; ++it) {
        const int cur = it & 1;
        const int ft  = s * 2048 + it * 64;

        float bb[2];
        bb[0] = bfc[ft + fw + c];
        bb[1] = bfc[ft + fw + 16 + c];

        if (it < 31) STAGE(cur ^ 1, it + 1)        // prefetch next tile

        // ---- stage 2: h[16m][32f] = t1 @ v1^T (2 nt x 4 kb MFMA)
        f32x4 c2[2] = {};
#pragma unroll
        for (int nt = 0; nt < 2; ++nt)
#pragma unroll
            for (int kb = 0; kb < 4; ++kb) {
                int row = fw + nt * 16 + c;
                f16x8 bv = *(const f16x8*)(smem + V1OFF + cur * 16384 +
                    row * 256 + ((kb * 64 + q * 16) ^ ((row & 15) << 4)));
                c2[nt] = MFMA16(a2[kb], bv, c2[nt]);
            }

        // ---- bias + gelu -> per-wave hs [16][HSTR]
#pragma unroll
        for (int nt = 0; nt < 2; ++nt)
#pragma unroll
            for (int i2 = 0; i2 < 4; ++i2)
                hsw[(q * 4 + i2) * HSTR + nt * 16 + c] =
                    (f16)gelu_fast(c2[nt][i2] + bb[nt]);
        asm volatile("s_waitcnt lgkmcnt(0)" ::: "memory"); // cross-lane RAW

        // ---- stage 3: c3 += h @ w2T^T (K=32, 8 rt MFMA)
        f16x8 a3 = *(const f16x8*)(hsw + c * HSTR + q * 8);
#pragma unroll
        for (int rt = 0; rt < 8; ++rt) {
            int rr = rt * 16 + c;
            f16x8 bw = *(const f16x8*)(smem + W2OFF + cur * 16384 +
                rr * 128 + ((wf * 64 + q * 16) ^ ((c & 7) << 4)));
            c3[rt] = MFMA16(a3, bw, c3[rt]);
        }
        asm volatile("s_waitcnt lgkmcnt(0)" ::: "memory"); // WAR on hs

        __syncthreads();   // next-tile loads landed + hs/tiles safe
    }
#undef STAGE

    // ---- epilogue: 2-wave reduce over wf (proven), write f16 t2p[s]
    float* rbuf = (float*)smem;

    if (wf == 1) {
        float* rb = rbuf + wm * 2112;
#pragma unroll
        for (int rt = 0; rt < 8; ++rt)
#pragma unroll
            for (int i2 = 0; i2 < 4; ++i2)
                rb[(q * 4 + i2) * 132 + rt * 16 + c] = c3[rt][i2];
    }
    __syncthreads();
    if (wf == 0) {
        float* rb = rbuf + wm * 2112;
#pragma unroll
        for (int rt = 0; rt < 8; ++rt)
#pragma unroll
            for (int i2 = 0; i2 < 4; ++i2)
                c3[rt][i2] += rb[(q * 4 + i2) * 132 + rt * 16 + c];
        f16* o = t2p + (size_t)s * (M_ROWS * RANK);
#pragma unroll
        for (int rt = 0; rt < 8; ++rt)
#pragma unroll
            for (int i2 = 0; i2 < 4; ++i2)
                o[(size_t)(m0b + wm * 16 + q * 4 + i2) * RANK + rt * 16 + c] =
                    (f16)c3[rt][i2];
    }
}

// ---------------------------------------------------------------------------
// Stage 4 (R1-set revert, proven R0/R1): out = (t2p0+t2p1) @ v2^T + bpj.
// 256 thr, BM=32, grid (256, 4).
// ---------------------------------------------------------------------------
__global__ __launch_bounds__(256, 2) void k_out(
    const f16* __restrict__ t2p, const f16* __restrict__ v2,
    const float* __restrict__ bpj, float* __restrict__ out)
{
    __shared__ __align__(16) f16 v2s[256 * 136];

    const int tid  = threadIdx.x;
    const int lane = tid & 63;
    const int wv   = tid >> 6;
    const int wm   = wv & 1, wn = wv >> 1;
    const int m0b  = blockIdx.x * 32;
    const int n0b  = blockIdx.y * 256;
    const int c    = lane & 15, q = lane >> 4;

#pragma unroll
    for (int i8 = 0; i8 < 16; ++i8) {
        int id = i8 * 256 + tid;
        int nn = id >> 4, k8 = id & 15;
        *(f16x8*)&v2s[nn * 136 + k8 * 8] =
            ld8(v2 + (size_t)(n0b + nn) * RANK + k8 * 8);
    }

    f16x8 a[4];
#pragma unroll
    for (int kb = 0; kb < 4; ++kb) {
        const size_t off = (size_t)(m0b + wm * 16 + c) * RANK + kb * 32 + q * 8;
        f16x8 p0 = ld8(t2p + off);
        f16x8 p1 = ld8(t2p + (size_t)(M_ROWS * RANK) + off);
#pragma unroll
        for (int e = 0; e < 8; ++e)
            a[kb][e] = (f16)((float)p0[e] + (float)p1[e]);
    }
    __syncthreads();

    f32x4 acc[8] = {};
#pragma unroll
    for (int nt = 0; nt < 8; ++nt)
#pragma unroll
        for (int kb = 0; kb < 4; ++kb) {
            f16x8 bf = *(const f16x8*)
                &v2s[(wn * 128 + nt * 16 + c) * 136 + kb * 32 + q * 8];
            acc[nt] = MFMA16(a[kb], bf, acc[nt]);
        }

#pragma unroll
    for (int nt = 0; nt < 8; ++nt) {
        float b = bpj[n0b + wn * 128 + nt * 16 + c];
#pragma unroll
        for (int i2 = 0; i2 < 4; ++i2)
            out[(size_t)(m0b + wm * 16 + q * 4 + i2) * D_MODEL +
                n0b + wn * 128 + nt * 16 + c] = acc[nt][i2] + b;
    }
}

extern "C" void kernel_launch(void* const* d_in, const int* in_sizes, int n_in,
                              void* d_out, int out_size, void* d_ws, size_t ws_size,
                              hipStream_t stream) {
    const float* x    = (const float*)d_in[0];
    const float* cfcU = (const float*)d_in[1];
    const float* cfcS = (const float*)d_in[2];
    const float* cfcV = (const float*)d_in[3];
    const float* cfcB = (const float*)d_in[4];
    const float* pjU  = (const float*)d_in[5];
    const float* pjS  = (const float*)d_in[6];
    const float* pjV  = (const float*)d_in[7];
    const float* pjB  = (const float*)d_in[8];
    float* out = (float*)d_out;

    // ws layout (f16 elements), 10.5 MB (12 MB proven safe):
    f16* wsf = (f16*)d_ws;
    f16* t1p = wsf;                 // [2][8192*128]  4 MB
    f16* t2p = wsf + 2097152;       // [2][8192*128]  4 MB
    f16* w1T = wsf + 4194304;       // [128*1024]
    f16* v1  = w1T + 131072;        // [4096*128]
    f16* w2T = v1  + 524288;        // [128*4096]
    f16* v2  = w2T + 524288;        // [1024*128]

    k_prep <<<dim3(5120), 256, 0, stream>>>(cfcU, cfcS, cfcV, pjU, pjS, pjV,
                                            w1T, v1, w2T, v2);
    k_t1   <<<dim3(M_ROWS / 64, 2), 512, 0, stream>>>(x, w1T, t1p);
    k_fused<<<dim3(512), 256, 0, stream>>>(t1p, v1, cfcB, w2T, t2p);
    k_out  <<<dim3(M_ROWS / 32, D_MODEL / 256), 256, 0, stream>>>(t2p, v2, pjB, out);
}